// Round 1
// 259.926 us; speedup vs baseline: 1.0221x; 1.0221x over previous
//
#include <hip/hip_runtime.h>

// MNIST_RNN R10: software-pipelined layers. R9 analysis: latency-bound —
// 2 waves/SIMD in lockstep, ~60% of wall is serial stall across ~8
// FENCE-ordered latency segments per timestep (DS drains, MFMA chains,
// exp chains). Fix: cell1(t) and cell0(t+1) are independent given h0(t);
// compute them TOGETHER each iteration -> one read phase (A1+A0), one
// MFMA phase (6 independent acc chains), one act phase, ONE gbuf
// round-trip (two buffers, one drain), one update phase (2 independent
// chains), one write phase. Serial segments per LSTM cell ~halve.
// Also: x bookkeeping as 32-bit element offsets + precomputed LDS
// offsets (saves ~14 VGPRs vs 64-bit pointer pairs).
// Numerics identical to R9 (same per-cell arithmetic/order).

#define HDIM 10
#define DDIM 28
#define TSTEPS 28

typedef __attribute__((ext_vector_type(8))) short short8;
typedef __attribute__((ext_vector_type(4))) float f32x4;

__device__ __forceinline__ unsigned short bf16_rne(float f) {
    unsigned u = __builtin_bit_cast(unsigned, f);
    u += 0x7FFFu + ((u >> 16) & 1u);
    return (unsigned short)(u >> 16);
}
__device__ __forceinline__ float bf16_f(unsigned short h) {
    unsigned u = ((unsigned)h) << 16;
    return __builtin_bit_cast(float, u);
}
// a=1: sigmoid(v); a=2: tanh(v)  [act = a*rcp(1+exp(-a*v)) + 1-a]
__device__ __forceinline__ float act_eval(float v, float a) {
    return a * __builtin_amdgcn_rcpf(1.0f + __expf(-a * v)) + (1.0f - a);
}

#define FENCE() __asm volatile("" ::: "memory")

__global__ __launch_bounds__(64) void lstm2_mfma_kernel(
    const float* __restrict__ x,
    const float* __restrict__ w_ih0, const float* __restrict__ w_hh0,
    const float* __restrict__ b_ih0, const float* __restrict__ b_hh0,
    const float* __restrict__ w_ih1, const float* __restrict__ w_hh1,
    const float* __restrict__ b_ih1, const float* __restrict__ b_hh1,
    const float* __restrict__ w_cls, const float* __restrict__ b_cls,
    float* __restrict__ out)
{
    // per-wave-private panels (block = 1 wave)
    __shared__ unsigned short uA0[16 * 136]; // A0 rows: [xhi28|h0hi10|xlo28|h0lo10|xhi28|h0hi10|pad14]
    __shared__ unsigned short uA1[16 * 72];  // A1 rows: [h0hi|h1hi|h0lo|h1lo|h0hi|h1hi|pad]
    __shared__ float gbuf0[48 * 20];         // activated L0 gates [n][m], Mpad=20
    __shared__ float gbuf1[48 * 20];         // activated L1 gates
    __shared__ float hfin[16 * 12];          // final h1 [m][u]

    const int l  = threadIdx.x;
    const int lm = l & 15;     // A-frag row m / B-frag & D col n / c-h unit u
    const int q  = l >> 4;     // quad: A/B k-offset 8q; D rows m=4q+r
    const int sbase = blockIdx.x * 16;

    // ---- zero A-panel pads (NaN*0=NaN in MFMA) ----
    for (int i = l; i < 16 * 22; i += 64) uA0[(i / 22) * 136 + 114 + (i % 22)] = 0;
    for (int i = l; i < 16 * 12; i += 64) uA1[(i / 12) * 72 + 60 + (i % 12)] = 0;

    // ---- build B-fragments in registers (once) ----
    short8 B0[3][4], B1[3][2];
    #pragma unroll
    for (int T = 0; T < 3; ++T) {
        const int n = lm + 16 * T;
        #pragma unroll
        for (int c = 0; c < 4; ++c) {
            #pragma unroll
            for (int j = 0; j < 8; ++j) {
                const int kk = 32 * c + 8 * q + j;
                unsigned short bits = 0;
                if (n < 40 && kk < 114) {
                    int k2 = kk, want_lo = 0;
                    if (k2 >= 76)      { k2 -= 76; want_lo = 1; }
                    else if (k2 >= 38) { k2 -= 38; }
                    const float w = (k2 < 28) ? w_ih0[n * 28 + k2]
                                              : w_hh0[n * 10 + (k2 - 28)];
                    const unsigned short hi = bf16_rne(w);
                    bits = want_lo ? bf16_rne(w - bf16_f(hi)) : hi;
                }
                B0[T][c][j] = (short)bits;
            }
        }
        #pragma unroll
        for (int c = 0; c < 2; ++c) {
            #pragma unroll
            for (int j = 0; j < 8; ++j) {
                const int kk = 32 * c + 8 * q + j;
                unsigned short bits = 0;
                if (n < 40 && kk < 60) {
                    int k2 = kk, want_lo = 0;
                    if (k2 >= 40)      { k2 -= 40; want_lo = 1; }
                    else if (k2 >= 20) { k2 -= 20; }
                    const float w = (k2 < 10) ? w_ih1[n * 10 + k2]
                                              : w_hh1[n * 10 + (k2 - 10)];
                    const unsigned short hi = bf16_rne(w);
                    bits = want_lo ? bf16_rne(w - bf16_f(hi)) : hi;
                }
                B1[T][c][j] = (short)bits;
            }
        }
    }

    // biases (folded into MFMA C-init) + per-tile activation selector
    float bias0[3], bias1[3], aT[3];
    #pragma unroll
    for (int T = 0; T < 3; ++T) {
        const int n = lm + 16 * T;
        bias0[T] = (n < 40) ? (b_ih0[n] + b_hh0[n]) : 0.0f;
        bias1[T] = (n < 40) ? (b_ih1[n] + b_hh1[n]) : 0.0f;
        aT[T] = (n >= 20 && n < 30) ? 2.0f : 1.0f;   // g-gate rows -> tanh
    }

    // ---- x pipeline: lane owns 7 of the 448 (sample,d) elements ----
    int xoff[7], lofs[7]; float xn[7];
    #pragma unroll
    for (int i = 0; i < 7; ++i) {
        const int f = l + 64 * i;
        const int sm = f / 28, d = f - 28 * sm;
        lofs[i] = sm * 136 + d;
        xoff[i] = (sbase + sm) * (TSTEPS * DDIM) + d;
        xn[i] = x[xoff[i]];            // t = 0
    }
    // write x(0) zones
    #pragma unroll
    for (int i = 0; i < 7; ++i) {
        const unsigned short hi = bf16_rne(xn[i]);
        const unsigned short lo = bf16_rne(xn[i] - bf16_f(hi));
        uA0[lofs[i]] = hi; uA0[lofs[i] + 38] = lo; uA0[lofs[i] + 76] = hi;
    }
    // zero h zones (h0 = h1 = 0 at t=0)
    if (lm < 10) {
        #pragma unroll
        for (int r = 0; r < 4; ++r) {
            const int m = 4 * q + r;
            unsigned short* r0 = &uA0[m * 136];
            r0[28 + lm] = 0; r0[66 + lm] = 0; r0[104 + lm] = 0;
            unsigned short* r1 = &uA1[m * 72];
            r1[lm] = 0; r1[20 + lm] = 0; r1[40 + lm] = 0;         // h0
            r1[10 + lm] = 0; r1[30 + lm] = 0; r1[50 + lm] = 0;    // h1
        }
    }
    FENCE();

    float c0s[4] = {0, 0, 0, 0}, c1s[4] = {0, 0, 0, 0};
    float h1v[4] = {0, 0, 0, 0};
    float h0v[4];
    short8 A0f[4], A1f[2];

    // ================= prologue: cell0(0) =================
    #pragma unroll
    for (int c = 0; c < 4; ++c)
        A0f[c] = *(const short8*)&uA0[lm * 136 + 32 * c + 8 * q];
    FENCE();
    // prefetch x(1)
    #pragma unroll
    for (int i = 0; i < 7; ++i) { xoff[i] += DDIM; xn[i] = x[xoff[i]]; }
    {
        f32x4 C[3];
        #pragma unroll
        for (int T = 0; T < 3; ++T) {
            f32x4 acc = {bias0[T], bias0[T], bias0[T], bias0[T]};
            #pragma unroll
            for (int c = 0; c < 4; ++c)
                acc = __builtin_amdgcn_mfma_f32_16x16x32_bf16(A0f[c], B0[T][c], acc, 0, 0, 0);
            C[T] = acc;
        }
        #pragma unroll
        for (int T = 0; T < 3; ++T) {
            f32x4 gv;
            #pragma unroll
            for (int r = 0; r < 4; ++r) gv[r] = act_eval(C[T][r], aT[T]);
            *(f32x4*)&gbuf0[(lm + 16 * T) * 20 + 4 * q] = gv;
        }
    }
    FENCE();
    {
        const f32x4 iv = *(const f32x4*)&gbuf0[(lm     ) * 20 + 4 * q];
        const f32x4 fv = *(const f32x4*)&gbuf0[(lm + 10) * 20 + 4 * q];
        const f32x4 gg = *(const f32x4*)&gbuf0[(lm + 20) * 20 + 4 * q];
        const f32x4 ov = *(const f32x4*)&gbuf0[(lm + 30) * 20 + 4 * q];
        #pragma unroll
        for (int r = 0; r < 4; ++r) {
            const float c = fv[r] * c0s[r] + iv[r] * gg[r];
            c0s[r] = c;
            h0v[r] = ov[r] * act_eval(c, 2.0f);
        }
        if (lm < 10) {
            #pragma unroll
            for (int r = 0; r < 4; ++r) {
                const int m = 4 * q + r;
                const unsigned short hi = bf16_rne(h0v[r]);
                const unsigned short lo = bf16_rne(h0v[r] - bf16_f(hi));
                unsigned short* r0 = &uA0[m * 136];
                r0[28 + lm] = hi; r0[66 + lm] = lo; r0[104 + lm] = hi;
                unsigned short* r1 = &uA1[m * 72];
                r1[lm] = hi; r1[20 + lm] = lo; r1[40 + lm] = hi;
            }
        }
    }
    FENCE();
    // write x(1) zones
    #pragma unroll
    for (int i = 0; i < 7; ++i) {
        const unsigned short hi = bf16_rne(xn[i]);
        const unsigned short lo = bf16_rne(xn[i] - bf16_f(hi));
        uA0[lofs[i]] = hi; uA0[lofs[i] + 38] = lo; uA0[lofs[i] + 76] = hi;
    }
    FENCE();

    // ===== main loop: iteration t computes cell1(t) AND cell0(t+1) =====
    #pragma unroll 1
    for (int t = 0; t < TSTEPS - 1; ++t) {
        // ---- read phase: A1 = {h0(t), h1(t-1)}, A0 = {x(t+1), h0(t)} ----
        #pragma unroll
        for (int c = 0; c < 2; ++c)
            A1f[c] = *(const short8*)&uA1[lm * 72 + 32 * c + 8 * q];
        #pragma unroll
        for (int c = 0; c < 4; ++c)
            A0f[c] = *(const short8*)&uA0[lm * 136 + 32 * c + 8 * q];
        FENCE();

        // prefetch x(t+2) into VGPRs (consumed at end of iteration)
        if (t < TSTEPS - 2) {
            #pragma unroll
            for (int i = 0; i < 7; ++i) { xoff[i] += DDIM; xn[i] = x[xoff[i]]; }
        }

        // ---- MFMA phase: 6 independent accumulator chains ----
        f32x4 C[3], D[3];
        #pragma unroll
        for (int T = 0; T < 3; ++T) {
            f32x4 accD = {bias1[T], bias1[T], bias1[T], bias1[T]};
            #pragma unroll
            for (int c = 0; c < 2; ++c)
                accD = __builtin_amdgcn_mfma_f32_16x16x32_bf16(A1f[c], B1[T][c], accD, 0, 0, 0);
            D[T] = accD;
            f32x4 accC = {bias0[T], bias0[T], bias0[T], bias0[T]};
            #pragma unroll
            for (int c = 0; c < 4; ++c)
                accC = __builtin_amdgcn_mfma_f32_16x16x32_bf16(A0f[c], B0[T][c], accC, 0, 0, 0);
            C[T] = accC;
        }

        // ---- act phase: both layers, one LDS store burst ----
        #pragma unroll
        for (int T = 0; T < 3; ++T) {
            f32x4 gv1, gv0;
            #pragma unroll
            for (int r = 0; r < 4; ++r) {
                gv1[r] = act_eval(D[T][r], aT[T]);
                gv0[r] = act_eval(C[T][r], aT[T]);
            }
            *(f32x4*)&gbuf1[(lm + 16 * T) * 20 + 4 * q] = gv1;
            *(f32x4*)&gbuf0[(lm + 16 * T) * 20 + 4 * q] = gv0;
        }
        FENCE();

        // ---- update phase: cell1(t) and cell0(t+1), independent chains ----
        {
            const f32x4 iv1 = *(const f32x4*)&gbuf1[(lm     ) * 20 + 4 * q];
            const f32x4 fv1 = *(const f32x4*)&gbuf1[(lm + 10) * 20 + 4 * q];
            const f32x4 gg1 = *(const f32x4*)&gbuf1[(lm + 20) * 20 + 4 * q];
            const f32x4 ov1 = *(const f32x4*)&gbuf1[(lm + 30) * 20 + 4 * q];
            const f32x4 iv0 = *(const f32x4*)&gbuf0[(lm     ) * 20 + 4 * q];
            const f32x4 fv0 = *(const f32x4*)&gbuf0[(lm + 10) * 20 + 4 * q];
            const f32x4 gg0 = *(const f32x4*)&gbuf0[(lm + 20) * 20 + 4 * q];
            const f32x4 ov0 = *(const f32x4*)&gbuf0[(lm + 30) * 20 + 4 * q];
            #pragma unroll
            for (int r = 0; r < 4; ++r) {
                const float c1 = fv1[r] * c1s[r] + iv1[r] * gg1[r];
                c1s[r] = c1;
                h1v[r] = ov1[r] * act_eval(c1, 2.0f);
                const float c0 = fv0[r] * c0s[r] + iv0[r] * gg0[r];
                c0s[r] = c0;
                h0v[r] = ov0[r] * act_eval(c0, 2.0f);
            }
            // ---- write phase: h1(t), h0(t+1) ----
            if (lm < 10) {
                #pragma unroll
                for (int r = 0; r < 4; ++r) {
                    const int m = 4 * q + r;
                    const unsigned short hi1 = bf16_rne(h1v[r]);
                    const unsigned short lo1 = bf16_rne(h1v[r] - bf16_f(hi1));
                    unsigned short* r1 = &uA1[m * 72];
                    r1[10 + lm] = hi1; r1[30 + lm] = lo1; r1[50 + lm] = hi1;
                    const unsigned short hi0 = bf16_rne(h0v[r]);
                    const unsigned short lo0 = bf16_rne(h0v[r] - bf16_f(hi0));
                    unsigned short* r0 = &uA0[m * 136];
                    r0[28 + lm] = hi0; r0[66 + lm] = lo0; r0[104 + lm] = hi0;
                    r1[lm] = hi0; r1[20 + lm] = lo0; r1[40 + lm] = hi0;
                }
            }
        }
        FENCE();

        // ---- write x(t+2) zones (loads long landed; after t's A0 reads) ----
        if (t < TSTEPS - 2) {
            #pragma unroll
            for (int i = 0; i < 7; ++i) {
                const unsigned short hi = bf16_rne(xn[i]);
                const unsigned short lo = bf16_rne(xn[i] - bf16_f(hi));
                uA0[lofs[i]] = hi; uA0[lofs[i] + 38] = lo; uA0[lofs[i] + 76] = hi;
            }
        }
        FENCE();
    }

    // ================= epilogue: cell1(27) =================
    {
        #pragma unroll
        for (int c = 0; c < 2; ++c)
            A1f[c] = *(const short8*)&uA1[lm * 72 + 32 * c + 8 * q];
        f32x4 D[3];
        #pragma unroll
        for (int T = 0; T < 3; ++T) {
            f32x4 acc = {bias1[T], bias1[T], bias1[T], bias1[T]};
            #pragma unroll
            for (int c = 0; c < 2; ++c)
                acc = __builtin_amdgcn_mfma_f32_16x16x32_bf16(A1f[c], B1[T][c], acc, 0, 0, 0);
            D[T] = acc;
        }
        #pragma unroll
        for (int T = 0; T < 3; ++T) {
            f32x4 gv;
            #pragma unroll
            for (int r = 0; r < 4; ++r) gv[r] = act_eval(D[T][r], aT[T]);
            *(f32x4*)&gbuf1[(lm + 16 * T) * 20 + 4 * q] = gv;
        }
        FENCE();
        const f32x4 iv = *(const f32x4*)&gbuf1[(lm     ) * 20 + 4 * q];
        const f32x4 fv = *(const f32x4*)&gbuf1[(lm + 10) * 20 + 4 * q];
        const f32x4 gg = *(const f32x4*)&gbuf1[(lm + 20) * 20 + 4 * q];
        const f32x4 ov = *(const f32x4*)&gbuf1[(lm + 30) * 20 + 4 * q];
        #pragma unroll
        for (int r = 0; r < 4; ++r) {
            const float c = fv[r] * c1s[r] + iv[r] * gg[r];
            h1v[r] = ov[r] * act_eval(c, 2.0f);
        }
    }

    // ---- classifier ----
    if (lm < 10) {
        #pragma unroll
        for (int r = 0; r < 4; ++r) hfin[(4 * q + r) * 12 + lm] = h1v[r];
    }
    FENCE();
    if (lm < 10) {
        float wc[10];
        #pragma unroll
        for (int j = 0; j < 10; ++j) wc[j] = w_cls[lm * 10 + j];
        const float bo = b_cls[lm];
        #pragma unroll
        for (int r = 0; r < 4; ++r) {
            const int m = 4 * q + r;
            float acc = bo;
            #pragma unroll
            for (int j = 0; j < 10; ++j) acc += hfin[m * 12 + j] * wc[j];
            out[(size_t)(sbase + m) * 10 + lm] = acc;
        }
    }
}

extern "C" void kernel_launch(void* const* d_in, const int* in_sizes, int n_in,
                              void* d_out, int out_size, void* d_ws, size_t ws_size,
                              hipStream_t stream) {
    const float* x     = (const float*)d_in[0];
    const float* w_ih0 = (const float*)d_in[1];
    const float* w_hh0 = (const float*)d_in[2];
    const float* b_ih0 = (const float*)d_in[3];
    const float* b_hh0 = (const float*)d_in[4];
    const float* w_ih1 = (const float*)d_in[5];
    const float* w_hh1 = (const float*)d_in[6];
    const float* b_ih1 = (const float*)d_in[7];
    const float* b_hh1 = (const float*)d_in[8];
    const float* w_cls = (const float*)d_in[9];
    const float* b_cls = (const float*)d_in[10];
    float* out = (float*)d_out;

    const int B = in_sizes[0] / (TSTEPS * DDIM);   // 32768
    const int grid = B / 16;                       // 2048 blocks of 1 wave

    hipLaunchKernelGGL(lstm2_mfma_kernel, dim3(grid), dim3(64), 0, stream,
                       x, w_ih0, w_hh0, b_ih0, b_hh0,
                       w_ih1, w_hh1, b_ih1, b_hh1,
                       w_cls, b_cls, out);
}